// Round 1
// baseline (104.448 us; speedup 1.0000x reference)
//
#include <hip/hip_runtime.h>
#include <hip/hip_bf16.h>

#define CIN 32
#define COUT 64
#define NB 4
#define NPTS 32768
#define KNN 16

typedef unsigned short u16;

__device__ __forceinline__ u16 f2bf(float f) {
  __hip_bfloat16 h = __float2bfloat16(f);
  u16 u; __builtin_memcpy(&u, &h, 2); return u;
}
__device__ __forceinline__ float bf2f(u16 u) {
  __hip_bfloat16 h; __builtin_memcpy(&h, &u, 2); return __bfloat162float(h);
}

// Kernel 1: local = W1@feat, edge = W2@feat, stored transposed (B,N,64) as bf16.
// Thread per n: feature column in 32 VGPRs, W accesses are wave-uniform -> s_load,
// 16 independent FMA chains per 16-channel chunk.
__global__ __launch_bounds__(256) void k1_gemm(
    const float* __restrict__ feat, const float* __restrict__ W1,
    const float* __restrict__ W2, u16* __restrict__ lt, u16* __restrict__ et) {
  const int b = blockIdx.y;
  const int n = blockIdx.x * 256 + threadIdx.x;
  float f[CIN];
  const float* fp = feat + (size_t)b * CIN * NPTS + n;
#pragma unroll
  for (int c = 0; c < CIN; ++c) f[c] = fp[(size_t)c * NPTS];
  const size_t obase = ((size_t)b * NPTS + n) * COUT;
#pragma unroll
  for (int half = 0; half < 2; ++half) {
    const float* Wp = half ? W2 : W1;
    u16* dst = half ? et : lt;
    for (int cc = 0; cc < 4; ++cc) {
      float acc[16];
#pragma unroll
      for (int j = 0; j < 16; ++j) acc[j] = 0.f;
      const float* wbase = Wp + (size_t)(cc * 16) * CIN;
#pragma unroll
      for (int c = 0; c < CIN; ++c) {
        const float fc = f[c];
#pragma unroll
        for (int j = 0; j < 16; ++j)
          acc[j] = fmaf(wbase[j * CIN + c], fc, acc[j]);
      }
#pragma unroll
      for (int jj = 0; jj < 4; ++jj) {
        ushort4 us;
        us.x = f2bf(acc[4 * jj + 0]);
        us.y = f2bf(acc[4 * jj + 1]);
        us.z = f2bf(acc[4 * jj + 2]);
        us.w = f2bf(acc[4 * jj + 3]);
        *reinterpret_cast<ushort4*>(dst + obase + cc * 16 + 4 * jj) = us;
      }
    }
  }
}

// Kernel 2: per (b,n): gather 16 neighbor rows (contiguous 128B bf16), BN+ReLU,
// mean over K. Wave layout: lane = kg*16+cg, kg handles k = p*4+kg, cg handles
// channels 4cg..4cg+3. shfl_xor(16,32) reduces over kg. Output staged in LDS
// (pad 17) then written as coalesced float4 (full 64B lines, 16 n per block).
__global__ __launch_bounds__(256) void k2_gather(
    const u16* __restrict__ lt, const u16* __restrict__ et,
    const int* __restrict__ knn, const float* __restrict__ gamma,
    const float* __restrict__ beta, const float* __restrict__ mean,
    const float* __restrict__ var, float* __restrict__ out) {
  __shared__ float obuf[128 * 17];
  const int nper = NPTS / 16;
  const int b = blockIdx.x / nper;
  const int n0 = (blockIdx.x % nper) * 16;
  const int t = threadIdx.x;
  const int w = t >> 6;
  const int lane = t & 63;
  const int kg = lane >> 4;
  const int cg = lane & 15;
  const int ch = cg * 4;

  float inv1[4], sh1[4], inv2[4], sh2[4];
#pragma unroll
  for (int j = 0; j < 4; ++j) {
    float iv = gamma[ch + j] / sqrtf(var[ch + j] + 1e-5f);
    inv1[j] = iv;
    sh1[j] = beta[ch + j] - mean[ch + j] * iv;
    float iv2 = gamma[64 + ch + j] / sqrtf(var[64 + ch + j] + 1e-5f);
    inv2[j] = iv2;
    sh2[j] = beta[64 + ch + j] - mean[64 + ch + j] * iv2;
  }

  for (int it = 0; it < 4; ++it) {
    const int nn = w * 4 + it;
    const int n = n0 + nn;
    const size_t row = (size_t)b * NPTS + n;
    const ushort4 lu = *reinterpret_cast<const ushort4*>(lt + row * COUT + ch);
    float lf[4] = {bf2f(lu.x), bf2f(lu.y), bf2f(lu.z), bf2f(lu.w)};
    const int* kp = knn + row * KNN;
    float acc[4] = {0.f, 0.f, 0.f, 0.f};
#pragma unroll
    for (int p = 0; p < 4; ++p) {
      const int idx = kp[p * 4 + kg];
      const ushort4 eu = *reinterpret_cast<const ushort4*>(
          et + ((size_t)b * NPTS + idx) * COUT + ch);
      float e0 = bf2f(eu.x), e1 = bf2f(eu.y), e2 = bf2f(eu.z), e3 = bf2f(eu.w);
      float d, v;
      d = e0 - lf[0]; v = fmaf(d, inv2[0], sh2[0]); acc[0] += fmaxf(v, 0.f);
      d = e1 - lf[1]; v = fmaf(d, inv2[1], sh2[1]); acc[1] += fmaxf(v, 0.f);
      d = e2 - lf[2]; v = fmaf(d, inv2[2], sh2[2]); acc[2] += fmaxf(v, 0.f);
      d = e3 - lf[3]; v = fmaf(d, inv2[3], sh2[3]); acc[3] += fmaxf(v, 0.f);
    }
#pragma unroll
    for (int j = 0; j < 4; ++j) {
      acc[j] += __shfl_xor(acc[j], 16);
      acc[j] += __shfl_xor(acc[j], 32);
    }
    if (kg == 0) {
#pragma unroll
      for (int j = 0; j < 4; ++j) {
        float r1 = fmaxf(fmaf(lf[j], inv1[j], sh1[j]), 0.f);
        obuf[(ch + j) * 17 + nn] = r1;                    // central half
        obuf[(64 + ch + j) * 17 + nn] = acc[j] * 0.0625f; // diff half, /16
      }
    }
  }
  __syncthreads();
  const size_t ob = (size_t)b * 128 * NPTS + n0;
#pragma unroll
  for (int q = 0; q < 2; ++q) {
    const int c = q * 64 + (t >> 2);
    const int nn4 = (t & 3) * 4;
    float4 v = make_float4(obuf[c * 17 + nn4 + 0], obuf[c * 17 + nn4 + 1],
                           obuf[c * 17 + nn4 + 2], obuf[c * 17 + nn4 + 3]);
    *reinterpret_cast<float4*>(out + ob + (size_t)c * NPTS + nn4) = v;
  }
}

extern "C" void kernel_launch(void* const* d_in, const int* in_sizes, int n_in,
                              void* d_out, int out_size, void* d_ws, size_t ws_size,
                              hipStream_t stream) {
  const float* feat  = (const float*)d_in[0];
  const int*   knn   = (const int*)d_in[1];
  const float* W1    = (const float*)d_in[2];
  const float* W2    = (const float*)d_in[3];
  const float* gamma = (const float*)d_in[4];
  const float* beta  = (const float*)d_in[5];
  const float* mean  = (const float*)d_in[6];
  const float* var   = (const float*)d_in[7];
  float* out = (float*)d_out;

  u16* lt = (u16*)d_ws;                       // (B,N,64) bf16 local
  u16* et = lt + (size_t)NB * NPTS * COUT;    // (B,N,64) bf16 edge
  // ws needed: 2 * 4*32768*64 * 2B = 32 MiB

  dim3 g1(NPTS / 256, NB);
  k1_gemm<<<g1, 256, 0, stream>>>(feat, W1, W2, lt, et);
  dim3 g2(NB * NPTS / 16);
  k2_gather<<<g2, 256, 0, stream>>>(lt, et, knn, gamma, beta, mean, var, out);
}

// Round 2
// 69.513 us; speedup vs baseline: 1.5026x; 1.5026x over previous
//
#include <hip/hip_runtime.h>
#include <hip/hip_fp16.h>

#define CIN 32
#define COUT 64
#define NB 4
#define NPTS 32768
#define KNN 16

typedef unsigned short u16;

__device__ __forceinline__ u16 f2h(float f) {
  _Float16 h = (_Float16)f;
  u16 u; __builtin_memcpy(&u, &h, 2); return u;
}
__device__ __forceinline__ float2 h2f2(unsigned int u) {
  __half2 h; __builtin_memcpy(&h, &u, 4); return __half22float2(h);
}

// Kernel 1: local = W1@feat, edge = W2@feat.
// Grid 2048 blocks x 256. Block = 64 consecutive n (lane = n), 4 waves each
// owning a wave-uniform 32-row chunk of [W1;W2] (readfirstlane -> s_load
// weights, FMA with SGPR operand). W1 waves additionally apply BN+ReLU and
// write the k-independent central output half directly (fp32, coalesced).
// Raw local/edge stored transposed (B,N,64) fp16 for k2's gather.
__global__ __launch_bounds__(256) void k1_gemm(
    const float* __restrict__ feat, const float* __restrict__ W1,
    const float* __restrict__ W2, const float* __restrict__ gamma,
    const float* __restrict__ beta, const float* __restrict__ mean,
    const float* __restrict__ var, u16* __restrict__ lt, u16* __restrict__ et,
    float* __restrict__ out) {
  const int bid = blockIdx.x;
  const int b = bid >> 9;             // 512 blocks per batch
  const int n0 = (bid & 511) << 6;    // 64 n per block
  const int t = threadIdx.x;
  const int lane = t & 63;
  const int wchunk = __builtin_amdgcn_readfirstlane(t >> 6);  // 0..3, uniform
  const int n = n0 + lane;

  float f[CIN];
  const float* fp = feat + (size_t)b * CIN * NPTS + n;
#pragma unroll
  for (int c = 0; c < CIN; ++c) f[c] = fp[(size_t)c * NPTS];

  const int half = wchunk >> 1;        // 0 -> W1 (local), 1 -> W2 (edge)
  const int rbase = (wchunk & 1) * 32; // channel rows [rbase, rbase+32)
  const float* Wp = half ? W2 : W1;
  u16* dst = half ? et : lt;

  unsigned int pk[16];  // 32 fp16 results packed

  for (int oo = 0; oo < 32; oo += 4) {
    const float* w0 = Wp + (size_t)(rbase + oo) * CIN;
    float a0 = 0.f, a1 = 0.f, a2 = 0.f, a3 = 0.f;
#pragma unroll
    for (int c = 0; c < CIN; ++c) {
      const float fc = f[c];
      a0 = fmaf(w0[c], fc, a0);
      a1 = fmaf(w0[CIN + c], fc, a1);
      a2 = fmaf(w0[2 * CIN + c], fc, a2);
      a3 = fmaf(w0[3 * CIN + c], fc, a3);
    }
    pk[oo / 2]     = (unsigned)f2h(a0) | ((unsigned)f2h(a1) << 16);
    pk[oo / 2 + 1] = (unsigned)f2h(a2) | ((unsigned)f2h(a3) << 16);
    if (half == 0) {
      // central output: relu(bn1(local)), exact f32 path
      const float acc[4] = {a0, a1, a2, a3};
#pragma unroll
      for (int i = 0; i < 4; ++i) {
        const int r = rbase + oo + i;
        const float iv = gamma[r] * rsqrtf(var[r] + 1e-5f);
        const float sh = beta[r] - mean[r] * iv;
        out[((size_t)b * 128 + r) * NPTS + n] = fmaxf(fmaf(acc[i], iv, sh), 0.f);
      }
    }
  }
  // store 32 fp16 = 4x uint4, row base is 128B-aligned, +rbase*2 keeps 16B align
  uint4* dp = reinterpret_cast<uint4*>(dst + ((size_t)(b * NPTS + n)) * COUT + rbase);
#pragma unroll
  for (int q = 0; q < 4; ++q)
    dp[q] = make_uint4(pk[4 * q], pk[4 * q + 1], pk[4 * q + 2], pk[4 * q + 3]);
}

// Kernel 2: diff half. Per (b,n): gather 16 neighbor rows (contiguous 128B),
// acc += relu(e*inv2 + (sh2 - lf*inv2)), mean over K. lane = kg*16+cg;
// shfl_xor(16,32) reduces over k-groups. XCD-swizzled blockIdx so each XCD's
// L2 keeps one batch's 4MiB edge table resident. Diff half staged in LDS
// (pad 17), written coalesced.
__global__ __launch_bounds__(256) void k2_gather(
    const u16* __restrict__ lt, const u16* __restrict__ et,
    const int* __restrict__ knn, const float* __restrict__ gamma,
    const float* __restrict__ beta, const float* __restrict__ mean,
    const float* __restrict__ var, float* __restrict__ out) {
  __shared__ float obuf[64 * 17];
  int bid = blockIdx.x;
  bid = (bid & 7) * 1024 + (bid >> 3);  // 8192 % 8 == 0 -> bijective
  const int b = bid >> 11;              // 2048 blocks per batch
  const int n0 = (bid & 2047) << 4;     // 16 n per block
  const int t = threadIdx.x;
  const int w = t >> 6;
  const int lane = t & 63;
  const int kg = lane >> 4;
  const int cg = lane & 15;
  const int ch = cg * 4;

  float inv2[4], sh2[4];
#pragma unroll
  for (int j = 0; j < 4; ++j) {
    const int r = 64 + ch + j;
    const float iv = gamma[r] * rsqrtf(var[r] + 1e-5f);
    inv2[j] = iv;
    sh2[j] = beta[r] - mean[r] * iv;
  }

  const size_t rowbase = (size_t)b * NPTS;
  for (int it = 0; it < 4; ++it) {
    const int nn = w * 4 + it;
    const int n = n0 + nn;
    const int* kp = knn + (rowbase + n) * KNN;
    int idx[4];
#pragma unroll
    for (int p = 0; p < 4; ++p) idx[p] = kp[p * 4 + kg];

    const uint2 lu = *reinterpret_cast<const uint2*>(lt + (rowbase + n) * COUT + ch);
    const float2 lf01 = h2f2(lu.x), lf23 = h2f2(lu.y);
    const float t0 = fmaf(-lf01.x, inv2[0], sh2[0]);
    const float t1 = fmaf(-lf01.y, inv2[1], sh2[1]);
    const float t2 = fmaf(-lf23.x, inv2[2], sh2[2]);
    const float t3 = fmaf(-lf23.y, inv2[3], sh2[3]);

    float acc0 = 0.f, acc1 = 0.f, acc2 = 0.f, acc3 = 0.f;
#pragma unroll
    for (int p = 0; p < 4; ++p) {
      const uint2 eu = *reinterpret_cast<const uint2*>(et + (rowbase + idx[p]) * COUT + ch);
      const float2 e01 = h2f2(eu.x), e23 = h2f2(eu.y);
      acc0 += fmaxf(fmaf(e01.x, inv2[0], t0), 0.f);
      acc1 += fmaxf(fmaf(e01.y, inv2[1], t1), 0.f);
      acc2 += fmaxf(fmaf(e23.x, inv2[2], t2), 0.f);
      acc3 += fmaxf(fmaf(e23.y, inv2[3], t3), 0.f);
    }
    acc0 += __shfl_xor(acc0, 16); acc0 += __shfl_xor(acc0, 32);
    acc1 += __shfl_xor(acc1, 16); acc1 += __shfl_xor(acc1, 32);
    acc2 += __shfl_xor(acc2, 16); acc2 += __shfl_xor(acc2, 32);
    acc3 += __shfl_xor(acc3, 16); acc3 += __shfl_xor(acc3, 32);
    if (kg == 0) {
      obuf[(ch + 0) * 17 + nn] = acc0 * 0.0625f;
      obuf[(ch + 1) * 17 + nn] = acc1 * 0.0625f;
      obuf[(ch + 2) * 17 + nn] = acc2 * 0.0625f;
      obuf[(ch + 3) * 17 + nn] = acc3 * 0.0625f;
    }
  }
  __syncthreads();
  const int c = t >> 2;
  const int nn4 = (t & 3) * 4;
  float4 v = make_float4(obuf[c * 17 + nn4], obuf[c * 17 + nn4 + 1],
                         obuf[c * 17 + nn4 + 2], obuf[c * 17 + nn4 + 3]);
  *reinterpret_cast<float4*>(out + ((size_t)b * 128 + 64 + c) * NPTS + n0 + nn4) = v;
}

extern "C" void kernel_launch(void* const* d_in, const int* in_sizes, int n_in,
                              void* d_out, int out_size, void* d_ws, size_t ws_size,
                              hipStream_t stream) {
  const float* feat  = (const float*)d_in[0];
  const int*   knn   = (const int*)d_in[1];
  const float* W1    = (const float*)d_in[2];
  const float* W2    = (const float*)d_in[3];
  const float* gamma = (const float*)d_in[4];
  const float* beta  = (const float*)d_in[5];
  const float* mean  = (const float*)d_in[6];
  const float* var   = (const float*)d_in[7];
  float* out = (float*)d_out;

  u16* lt = (u16*)d_ws;                     // (B,N,64) fp16 raw local
  u16* et = lt + (size_t)NB * NPTS * COUT;  // (B,N,64) fp16 edge
  // ws: 32 MiB

  k1_gemm<<<dim3(NB * NPTS / 64), 256, 0, stream>>>(feat, W1, W2, gamma, beta,
                                                    mean, var, lt, et, out);
  k2_gather<<<dim3(NB * NPTS / 16), 256, 0, stream>>>(lt, et, knn, gamma, beta,
                                                      mean, var, out);
}

// Round 4
// 64.707 us; speedup vs baseline: 1.6142x; 1.0743x over previous
//
#include <hip/hip_runtime.h>
#include <hip/hip_fp16.h>

#define CIN 32
#define COUT 64
#define NB 4
#define NPTS 32768
#define KNN 16

typedef unsigned short u16;
typedef _Float16 h2 __attribute__((ext_vector_type(2)));

__device__ __forceinline__ u16 f2h(float f) {
  _Float16 h = (_Float16)f;
  u16 u; __builtin_memcpy(&u, &h, 2); return u;
}
__device__ __forceinline__ h2 u2h2(unsigned int u) {
  h2 h; __builtin_memcpy(&h, &u, 4); return h;
}
__device__ __forceinline__ unsigned int h22u(h2 h) {
  unsigned int u; __builtin_memcpy(&u, &h, 4); return u;
}

// Kernel 1: local = W1@feat, edge = W2@feat.
// Grid 2048 blocks x 256. Block = 64 consecutive n (lane = n), 4 waves each
// owning a wave-uniform 32-row chunk of [W1;W2] (readfirstlane -> s_load
// weights). W1 waves also apply BN+ReLU and write the k-independent central
// output half directly (fp32, coalesced). Raw local/edge stored transposed
// (B,N,64) fp16 for k2's gather.
__global__ __launch_bounds__(256) void k1_gemm(
    const float* __restrict__ feat, const float* __restrict__ W1,
    const float* __restrict__ W2, const float* __restrict__ gamma,
    const float* __restrict__ beta, const float* __restrict__ mean,
    const float* __restrict__ var, u16* __restrict__ lt, u16* __restrict__ et,
    float* __restrict__ out) {
  const int bid = blockIdx.x;
  const int b = bid >> 9;
  const int n0 = (bid & 511) << 6;
  const int t = threadIdx.x;
  const int lane = t & 63;
  const int wchunk = __builtin_amdgcn_readfirstlane(t >> 6);
  const int n = n0 + lane;

  float f[CIN];
  const float* fp = feat + (size_t)b * CIN * NPTS + n;
#pragma unroll
  for (int c = 0; c < CIN; ++c) f[c] = fp[(size_t)c * NPTS];

  const int half = wchunk >> 1;
  const int rbase = (wchunk & 1) * 32;
  const float* Wp = half ? W2 : W1;
  u16* dst = half ? et : lt;

  unsigned int pk[16];

#pragma unroll
  for (int oo = 0; oo < 32; oo += 4) {
    const float* w0 = Wp + (size_t)(rbase + oo) * CIN;
    float a0 = 0.f, a1 = 0.f, a2 = 0.f, a3 = 0.f;
#pragma unroll
    for (int c = 0; c < CIN; ++c) {
      const float fc = f[c];
      a0 = fmaf(w0[c], fc, a0);
      a1 = fmaf(w0[CIN + c], fc, a1);
      a2 = fmaf(w0[2 * CIN + c], fc, a2);
      a3 = fmaf(w0[3 * CIN + c], fc, a3);
    }
    pk[oo / 2]     = (unsigned)f2h(a0) | ((unsigned)f2h(a1) << 16);
    pk[oo / 2 + 1] = (unsigned)f2h(a2) | ((unsigned)f2h(a3) << 16);
    if (half == 0) {
      const float acc[4] = {a0, a1, a2, a3};
#pragma unroll
      for (int i = 0; i < 4; ++i) {
        const int r = rbase + oo + i;
        const float iv = gamma[r] * rsqrtf(var[r] + 1e-5f);
        const float sh = beta[r] - mean[r] * iv;
        out[((size_t)b * 128 + r) * NPTS + n] = fmaxf(fmaf(acc[i], iv, sh), 0.f);
      }
    }
  }
  uint4* dp = reinterpret_cast<uint4*>(dst + ((size_t)(b * NPTS + n)) * COUT + rbase);
#pragma unroll
  for (int q = 0; q < 4; ++q)
    dp[q] = make_uint4(pk[4 * q], pk[4 * q + 1], pk[4 * q + 2], pk[4 * q + 3]);
}

// Kernel 2: diff half, packed-fp16 math (v_pk_fma/max/add via ext_vector).
// lane = kg*8+cg: kg in [0,8) covers k = {kg, kg+8}, cg in [0,8) covers
// channels 8cg..8cg+7 as 4x half2 (uint4 gathers: 8 lanes read one 128B row).
// Reduce over kg via 3 shfl_xor levels in fp16. XCD-swizzled blockIdx for L2
// locality. Diff half staged in LDS (pad 17), written coalesced as float4.
__global__ __launch_bounds__(256) void k2_gather(
    const u16* __restrict__ lt, const u16* __restrict__ et,
    const int* __restrict__ knn, const float* __restrict__ gamma,
    const float* __restrict__ beta, const float* __restrict__ mean,
    const float* __restrict__ var, float* __restrict__ out) {
  __shared__ float obuf[64 * 17];
  int bid = blockIdx.x;
  bid = (bid & 7) * 1024 + (bid >> 3);  // 8192 % 8 == 0 -> bijective
  const int b = bid >> 11;
  const int n0 = (bid & 2047) << 4;
  const int t = threadIdx.x;
  const int w = t >> 6;
  const int lane = t & 63;
  const int kg = lane >> 3;       // 0..7
  const int cg = lane & 7;        // 0..7
  const int ch = cg * 8;          // 8 channels per lane

  // packed BN constants for channels 64+ch .. 64+ch+7
  h2 inv_h2[4], sh_h2[4];
#pragma unroll
  for (int i = 0; i < 4; ++i) {
    const int r0 = 64 + ch + 2 * i;
    const float iv0 = gamma[r0] * rsqrtf(var[r0] + 1e-5f);
    const float iv1 = gamma[r0 + 1] * rsqrtf(var[r0 + 1] + 1e-5f);
    const float s0 = beta[r0] - mean[r0] * iv0;
    const float s1 = beta[r0 + 1] - mean[r0 + 1] * iv1;
    inv_h2[i] = (h2){(_Float16)iv0, (_Float16)iv1};
    sh_h2[i] = (h2){(_Float16)s0, (_Float16)s1};
  }

  const size_t rowbase = (size_t)b * NPTS;
  const u16* etb = et + rowbase * COUT + ch;  // 16B-aligned per-lane base
  const u16* ltb = lt + rowbase * COUT + ch;

  // ---- phase 1: issue all loads for 4 n ----
  int i0[4], i1[4];
  uint4 lv[4], e0[4], e1[4];
#pragma unroll
  for (int it = 0; it < 4; ++it) {
    const int n = n0 + w * 4 + it;
    const int* kp = knn + (rowbase + n) * KNN;
    i0[it] = kp[kg];
    i1[it] = kp[kg + 8];
    lv[it] = *reinterpret_cast<const uint4*>(ltb + (size_t)n * COUT);
  }
#pragma unroll
  for (int it = 0; it < 4; ++it) {
    e0[it] = *reinterpret_cast<const uint4*>(etb + ((size_t)i0[it] << 6));
    e1[it] = *reinterpret_cast<const uint4*>(etb + ((size_t)i1[it] << 6));
  }

  // ---- phase 2: math ----
  const h2 zero = (h2){(_Float16)0.f, (_Float16)0.f};
#pragma unroll
  for (int it = 0; it < 4; ++it) {
    const int nn = w * 4 + it;
    const unsigned int* lu = reinterpret_cast<const unsigned int*>(&lv[it]);
    const unsigned int* a0 = reinterpret_cast<const unsigned int*>(&e0[it]);
    const unsigned int* a1 = reinterpret_cast<const unsigned int*>(&e1[it]);
    unsigned int accu[4];
#pragma unroll
    for (int i = 0; i < 4; ++i) {
      const h2 tt = sh_h2[i] - u2h2(lu[i]) * inv_h2[i];
      h2 acc = __builtin_elementwise_max(u2h2(a0[i]) * inv_h2[i] + tt, zero);
      acc = acc + __builtin_elementwise_max(u2h2(a1[i]) * inv_h2[i] + tt, zero);
      accu[i] = h22u(acc);
    }
    // reduce over kg: xor 8, 16, 32
#pragma unroll
    for (int i = 0; i < 4; ++i) {
      unsigned int v = accu[i];
      v = h22u(u2h2(v) + u2h2((unsigned)__shfl_xor((int)v, 8)));
      v = h22u(u2h2(v) + u2h2((unsigned)__shfl_xor((int)v, 16)));
      v = h22u(u2h2(v) + u2h2((unsigned)__shfl_xor((int)v, 32)));
      accu[i] = v;
    }
    if (kg == 0) {
      const float inv16 = 0.0625f;
#pragma unroll
      for (int i = 0; i < 4; ++i) {
        const h2 fv = u2h2(accu[i]);
        obuf[(ch + 2 * i) * 17 + nn] = (float)fv.x * inv16;
        obuf[(ch + 2 * i + 1) * 17 + nn] = (float)fv.y * inv16;
      }
    }
  }
  __syncthreads();
  const int c = t >> 2;
  const int nn4 = (t & 3) * 4;
  float4 v = make_float4(obuf[c * 17 + nn4], obuf[c * 17 + nn4 + 1],
                         obuf[c * 17 + nn4 + 2], obuf[c * 17 + nn4 + 3]);
  *reinterpret_cast<float4*>(out + ((size_t)b * 128 + 64 + c) * NPTS + n0 + nn4) = v;
}

extern "C" void kernel_launch(void* const* d_in, const int* in_sizes, int n_in,
                              void* d_out, int out_size, void* d_ws, size_t ws_size,
                              hipStream_t stream) {
  const float* feat  = (const float*)d_in[0];
  const int*   knn   = (const int*)d_in[1];
  const float* W1    = (const float*)d_in[2];
  const float* W2    = (const float*)d_in[3];
  const float* gamma = (const float*)d_in[4];
  const float* beta  = (const float*)d_in[5];
  const float* mean  = (const float*)d_in[6];
  const float* var   = (const float*)d_in[7];
  float* out = (float*)d_out;

  u16* lt = (u16*)d_ws;
  u16* et = lt + (size_t)NB * NPTS * COUT;

  k1_gemm<<<dim3(NB * NPTS / 64), 256, 0, stream>>>(feat, W1, W2, gamma, beta,
                                                    mean, var, lt, et, out);
  k2_gather<<<dim3(NB * NPTS / 16), 256, 0, stream>>>(lt, et, knn, gamma, beta,
                                                      mean, var, out);
}

// Round 5
// 55.070 us; speedup vs baseline: 1.8966x; 1.1750x over previous
//
#include <hip/hip_runtime.h>
#include <hip/hip_fp16.h>

#define CIN 32
#define COUT 64
#define NB 4
#define NPTS 32768
#define KNN 16

typedef unsigned short u16;
typedef unsigned char u8;
typedef float f2v __attribute__((ext_vector_type(2)));

__device__ __forceinline__ u16 f2h(float f) {
  _Float16 h = (_Float16)f;
  u16 u; __builtin_memcpy(&u, &h, 2); return u;
}
__device__ __forceinline__ f2v h2_to_f2(unsigned int u) {
  _Float16 a, b;
  __builtin_memcpy(&a, (const char*)&u, 2);
  __builtin_memcpy(&b, ((const char*)&u) + 2, 2);
  return (f2v){(float)a, (float)b};
}

// Kernel 1: local = W1@feat, edge = W2@feat, via v_pk_fma_f32 (float2 pairs
// over the CIN axis; weight pairs are consecutive in memory -> s_load pairs).
// Grid 2048x256; block = 64 n; 4 waves each own a uniform 32-row chunk of
// [W1;W2]. W1 waves apply BN+ReLU and write the k-independent central output
// half (fp32, coalesced) + raw local as fp16 (B,N,64). W2 waves write the
// edge table as fp8 e4m3 (B,N,64) -> 2 MiB/batch so it stays L2-resident.
__global__ __launch_bounds__(256) void k1_gemm(
    const float* __restrict__ feat, const float* __restrict__ W1,
    const float* __restrict__ W2, const float* __restrict__ gamma,
    const float* __restrict__ beta, const float* __restrict__ mean,
    const float* __restrict__ var, u16* __restrict__ lt, u8* __restrict__ et,
    float* __restrict__ out) {
  const int bid = blockIdx.x;
  const int b = bid >> 9;
  const int n0 = (bid & 511) << 6;
  const int t = threadIdx.x;
  const int lane = t & 63;
  const int wchunk = __builtin_amdgcn_readfirstlane(t >> 6);
  const int n = n0 + lane;

  f2v fv[16];
  const float* fp = feat + (size_t)b * CIN * NPTS + n;
#pragma unroll
  for (int c2 = 0; c2 < 16; ++c2)
    fv[c2] = (f2v){fp[(size_t)(2 * c2) * NPTS], fp[(size_t)(2 * c2 + 1) * NPTS]};

  const int half = wchunk >> 1;        // 0 -> W1 (local), 1 -> W2 (edge fp8)
  const int rbase = (wchunk & 1) * 32;
  const float* Wp = half ? W2 : W1;

  unsigned int pkh[16];  // fp16 pack (local waves)
  unsigned int pk8[8];   // fp8 pack (edge waves)

#pragma unroll
  for (int oo = 0; oo < 32; oo += 4) {
    const float* w0 = Wp + (size_t)(rbase + oo) * CIN;
    const f2v* wr0 = reinterpret_cast<const f2v*>(w0);
    const f2v* wr1 = reinterpret_cast<const f2v*>(w0 + CIN);
    const f2v* wr2 = reinterpret_cast<const f2v*>(w0 + 2 * CIN);
    const f2v* wr3 = reinterpret_cast<const f2v*>(w0 + 3 * CIN);
    f2v p0 = (f2v)0.f, p1 = (f2v)0.f, p2 = (f2v)0.f, p3 = (f2v)0.f;
#pragma unroll
    for (int c2 = 0; c2 < 16; ++c2) {
      const f2v fc = fv[c2];
      p0 = __builtin_elementwise_fma(wr0[c2], fc, p0);
      p1 = __builtin_elementwise_fma(wr1[c2], fc, p1);
      p2 = __builtin_elementwise_fma(wr2[c2], fc, p2);
      p3 = __builtin_elementwise_fma(wr3[c2], fc, p3);
    }
    const float a0 = p0.x + p0.y, a1 = p1.x + p1.y;
    const float a2 = p2.x + p2.y, a3 = p3.x + p3.y;
    if (half == 0) {
      pkh[oo / 2]     = (unsigned)f2h(a0) | ((unsigned)f2h(a1) << 16);
      pkh[oo / 2 + 1] = (unsigned)f2h(a2) | ((unsigned)f2h(a3) << 16);
      const float acc[4] = {a0, a1, a2, a3};
#pragma unroll
      for (int i = 0; i < 4; ++i) {
        const int r = rbase + oo + i;
        const float iv = gamma[r] * rsqrtf(var[r] + 1e-5f);
        const float sh = beta[r] - mean[r] * iv;
        out[((size_t)b * 128 + r) * NPTS + n] = fmaxf(fmaf(acc[i], iv, sh), 0.f);
      }
    } else {
      int u = 0;
      u = __builtin_amdgcn_cvt_pk_fp8_f32(a0, a1, u, false);
      u = __builtin_amdgcn_cvt_pk_fp8_f32(a2, a3, u, true);
      pk8[oo / 4] = (unsigned)u;
    }
  }
  if (half == 0) {
    uint4* dp = reinterpret_cast<uint4*>(lt + ((size_t)(b * NPTS + n)) * COUT + rbase);
#pragma unroll
    for (int q = 0; q < 4; ++q)
      dp[q] = make_uint4(pkh[4 * q], pkh[4 * q + 1], pkh[4 * q + 2], pkh[4 * q + 3]);
  } else {
    uint4* dp = reinterpret_cast<uint4*>(et + ((size_t)(b * NPTS + n)) * COUT + rbase);
    dp[0] = make_uint4(pk8[0], pk8[1], pk8[2], pk8[3]);
    dp[1] = make_uint4(pk8[4], pk8[5], pk8[6], pk8[7]);
  }
}

// Kernel 2: diff half. All K=16 in-lane (no shuffles, no cross-lane reduce).
// lane = nn*8+cg: thread owns (n = n0+w*8+nn, channels 8cg..8cg+7), gathers
// 16 fp8 rows (8B uint2 each; 8 lanes cover one 64B row = 1 cache line),
// decodes via v_cvt_pk_f32_fp8, accumulates with v_pk_fma/max/add_f32.
// XCD-swizzled grid pins each batch's 2 MiB table to 2 XCDs' L2. Output
// staged in LDS, written as coalesced float4.
__global__ __launch_bounds__(256) void k2_gather(
    const u16* __restrict__ lt, const u8* __restrict__ et,
    const int* __restrict__ knn, const float* __restrict__ gamma,
    const float* __restrict__ beta, const float* __restrict__ mean,
    const float* __restrict__ var, float* __restrict__ out) {
  __shared__ float obuf[64 * 33];
  int bid = blockIdx.x;
  bid = (bid & 7) * 512 + (bid >> 3);   // 4096 % 8 == 0 -> bijective
  const int b = bid >> 10;              // 1024 blocks per batch
  const int n_blk = (bid & 1023) << 5;  // 32 n per block
  const int t = threadIdx.x;
  const int w = t >> 6;
  const int lane = t & 63;
  const int nn = lane >> 3;   // 0..7
  const int cg = lane & 7;    // 0..7
  const int ch = cg * 8;      // 8 channels per lane

  f2v inv[4], sh[4];
#pragma unroll
  for (int i = 0; i < 4; ++i) {
    const int r0 = 64 + ch + 2 * i;
    const float iv0 = gamma[r0] * rsqrtf(var[r0] + 1e-5f);
    const float iv1 = gamma[r0 + 1] * rsqrtf(var[r0 + 1] + 1e-5f);
    inv[i] = (f2v){iv0, iv1};
    sh[i] = (f2v){beta[r0] - mean[r0] * iv0, beta[r0 + 1] - mean[r0 + 1] * iv1};
  }

  const int n = n_blk + w * 8 + nn;
  const size_t rowbase = (size_t)b * NPTS;

  // knn row: 16 idx = 4x int4 (64B, broadcast across the 8 cg lanes)
  const int4* kp = reinterpret_cast<const int4*>(knn + (rowbase + n) * KNN);
  const int4 kv0 = kp[0], kv1 = kp[1], kv2 = kp[2], kv3 = kp[3];
  // local row: 8 fp16 = 16B
  const uint4 lv = *reinterpret_cast<const uint4*>(lt + (rowbase + n) * COUT + ch);

  // issue all 16 gathers (8B fp8 each)
  const u8* etb = et + rowbase * COUT + ch;
  uint2 e[16];
  const int idx[16] = {kv0.x, kv0.y, kv0.z, kv0.w, kv1.x, kv1.y, kv1.z, kv1.w,
                       kv2.x, kv2.y, kv2.z, kv2.w, kv3.x, kv3.y, kv3.z, kv3.w};
#pragma unroll
  for (int k = 0; k < 16; ++k)
    e[k] = *reinterpret_cast<const uint2*>(etb + ((size_t)idx[k] << 6));

  // tt_i = sh_i - local_i * inv_i
  const unsigned int* lu = reinterpret_cast<const unsigned int*>(&lv);
  f2v tt[4];
#pragma unroll
  for (int i = 0; i < 4; ++i) tt[i] = sh[i] - h2_to_f2(lu[i]) * inv[i];

  f2v acc[4] = {(f2v)0.f, (f2v)0.f, (f2v)0.f, (f2v)0.f};
  const f2v zero = (f2v)0.f;
#pragma unroll
  for (int k = 0; k < 16; ++k) {
    const f2v d0 = __builtin_amdgcn_cvt_pk_f32_fp8(e[k].x, false);
    const f2v d1 = __builtin_amdgcn_cvt_pk_f32_fp8(e[k].x, true);
    const f2v d2 = __builtin_amdgcn_cvt_pk_f32_fp8(e[k].y, false);
    const f2v d3 = __builtin_amdgcn_cvt_pk_f32_fp8(e[k].y, true);
    acc[0] += __builtin_elementwise_max(__builtin_elementwise_fma(d0, inv[0], tt[0]), zero);
    acc[1] += __builtin_elementwise_max(__builtin_elementwise_fma(d1, inv[1], tt[1]), zero);
    acc[2] += __builtin_elementwise_max(__builtin_elementwise_fma(d2, inv[2], tt[2]), zero);
    acc[3] += __builtin_elementwise_max(__builtin_elementwise_fma(d3, inv[3], tt[3]), zero);
  }

  const int ncol = w * 8 + nn;
#pragma unroll
  for (int i = 0; i < 4; ++i) {
    obuf[(ch + 2 * i) * 33 + ncol] = acc[i].x * 0.0625f;
    obuf[(ch + 2 * i + 1) * 33 + ncol] = acc[i].y * 0.0625f;
  }
  __syncthreads();
#pragma unroll
  for (int r = 0; r < 2; ++r) {
    const int c = (t >> 3) + (r << 5);
    const int nn4 = (t & 7) * 4;
    float4 v = make_float4(obuf[c * 33 + nn4], obuf[c * 33 + nn4 + 1],
                           obuf[c * 33 + nn4 + 2], obuf[c * 33 + nn4 + 3]);
    *reinterpret_cast<float4*>(out + ((size_t)b * 128 + 64 + c) * NPTS + n_blk + nn4) = v;
  }
}

extern "C" void kernel_launch(void* const* d_in, const int* in_sizes, int n_in,
                              void* d_out, int out_size, void* d_ws, size_t ws_size,
                              hipStream_t stream) {
  const float* feat  = (const float*)d_in[0];
  const int*   knn   = (const int*)d_in[1];
  const float* W1    = (const float*)d_in[2];
  const float* W2    = (const float*)d_in[3];
  const float* gamma = (const float*)d_in[4];
  const float* beta  = (const float*)d_in[5];
  const float* mean  = (const float*)d_in[6];
  const float* var   = (const float*)d_in[7];
  float* out = (float*)d_out;

  u16* lt = (u16*)d_ws;                       // (B,N,64) fp16 local, 16.8 MB
  u8* et = (u8*)(lt + (size_t)NB * NPTS * COUT);  // (B,N,64) fp8 edge, 8.4 MB

  k1_gemm<<<dim3(NB * NPTS / 64), 256, 0, stream>>>(feat, W1, W2, gamma, beta,
                                                    mean, var, lt, et, out);
  k2_gather<<<dim3(NB * NPTS / 32), 256, 0, stream>>>(lt, et, knn, gamma, beta,
                                                      mean, var, out);
}